// Round 4
// baseline (1253.546 us; speedup 1.0000x reference)
//
#include <hip/hip_runtime.h>

#define NH 6
#define NTOK 49
#define CDIM 192
#define NWIN 1024
#define SCALE 0.17677669529663687f

typedef __bf16 bf16x8 __attribute__((ext_vector_type(8)));
typedef float f32x4 __attribute__((ext_vector_type(4)));
typedef unsigned short u16;
typedef u16 u16x8 __attribute__((ext_vector_type(8)));
typedef unsigned int u32;

__device__ __forceinline__ u16 f2bf(float x) {
    u32 u = __builtin_bit_cast(u32, x);
    u = (u + 0x7FFFu + ((u >> 16) & 1u)) >> 16;
    return (u16)u;
}

__global__ void build_wb(const float* __restrict__ w, u16* __restrict__ wb) {
    int i = blockIdx.x * 256 + threadIdx.x;
    if (i < CDIM * CDIM) wb[i] = f2bf(w[i]);
}

// One block per window, 256 threads = 4 waves. Per-head fused proj:
// out = sum_h x_h @ W_h^T, wave wv owns out rows 16wv..16wv+15 (its own PV
// rows) x all 192 cols -> no cross-wave x exchange, no xb buffer.
// Double-buffered k_s/vT + reg-prefetch of Q/K/V one head ahead -> ONE
// barrier per head; p_s stripes are wave-private (no barrier ever).
__global__ __launch_bounds__(256, 4)
void swin_attn(const float* __restrict__ qkv, const int* __restrict__ rpi,
               const float* __restrict__ mask, const float* __restrict__ bias_table,
               const u16* __restrict__ wb, const float* __restrict__ proj_b,
               float* __restrict__ out) {
    __shared__ u16 k_s[2][64][40];   // K bf16, row 80B (2-way alias, free)
    __shared__ u16 vT_s[2][32][72];  // V^T bf16 [d][n], row 144B
    __shared__ u16 p_s[64][72];      // P then x_h, wave-private 16-row stripes

    const int tid = threadIdx.x;
    const int b = blockIdx.x;
    const int wn = b & (NWIN - 1);
    const int wv = tid >> 6;
    const int lane = tid & 63;
    const int lg = lane >> 4;
    const int lc = lane & 15;

    const float* qkvb = qkv + (size_t)b * (NTOK * 3 * CDIM);
    const float* mrow = mask + (size_t)wn * (NTOK * NTOK);
    const f32x4 fzero = {0.f, 0.f, 0.f, 0.f};

    // staging distribution: item idx in [0,392): n=idx>>3, f=idx&7
    const int n0 = tid >> 3, f0 = tid & 7;
    const bool s1 = tid < 136;
    const int n1 = (tid + 256) >> 3, f1 = (tid + 256) & 7;

    // this lane's Q row (A-frag needs 32B contiguous of one row; wave-private)
    const int qrow = (16 * wv + lc < NTOK) ? 16 * wv + lc : NTOK - 1;
    const float* qptr = qkvb + (size_t)qrow * 576 + 8 * lg;

    // ---- prologue: issue h=0 loads ----
    float4 qpA = *reinterpret_cast<const float4*>(qptr);
    float4 qpB = *reinterpret_cast<const float4*>(qptr + 4);
    float4 kp0 = *reinterpret_cast<const float4*>(qkvb + n0 * 576 + CDIM + f0 * 4);
    float4 vp0 = *reinterpret_cast<const float4*>(qkvb + n0 * 576 + 2 * CDIM + f0 * 4);
    float4 kp1 = {0, 0, 0, 0}, vp1 = {0, 0, 0, 0};
    if (s1) {
        kp1 = *reinterpret_cast<const float4*>(qkvb + n1 * 576 + CDIM + f1 * 4);
        vp1 = *reinterpret_cast<const float4*>(qkvb + n1 * 576 + 2 * CDIM + f1 * 4);
    }

    // ---- hoist rpi/mask: 8 packed index regs + 2 bitmask regs ----
    u32 bidx2[8];
    u32 mbits = 0, vbits = 0;
#pragma unroll
    for (int r = 0; r < 4; ++r) {
        const int i = 16 * wv + 4 * lg + r;
#pragma unroll
        for (int t = 0; t < 4; ++t) {
            const int j = 16 * t + lc;
            const int idx = r * 4 + t;
            const bool valid = (i < NTOK) && (j < NTOK);
            const int ij = valid ? i * NTOK + j : 0;
            const u32 bi = (u32)(rpi[ij] * NH);  // < 1014, fits 16 bits
            if (idx & 1) bidx2[idx >> 1] |= bi << 16; else bidx2[idx >> 1] = bi;
            const float mv = valid ? mrow[ij] : 0.f;
            if (!valid) vbits |= 1u << idx;
            if (mv < -50.f) mbits |= 1u << idx;
        }
    }

    // ---- zero pads once: k_s rows 49..63 (both bufs), vT cols 49..63 ----
    for (int idx = tid; idx < 480; idx += 256) {
        const int rr = idx >> 5, cc = idx & 31;
        k_s[0][49 + rr][cc] = 0;
        k_s[1][49 + rr][cc] = 0;
    }
    for (int idx = tid; idx < 512; idx += 256) {
        const int d = idx >> 4, m = idx & 15;
        if (m) { vT_s[0][d][48 + m] = 0; vT_s[1][d][48 + m] = 0; }
    }

    // ---- stage h=0 into buffer 0 ----
    {
        ushort4 o;
        o.x = f2bf(kp0.x); o.y = f2bf(kp0.y); o.z = f2bf(kp0.z); o.w = f2bf(kp0.w);
        *reinterpret_cast<ushort4*>(&k_s[0][n0][f0 * 4]) = o;
        const int d0 = f0 * 4;
        vT_s[0][d0 + 0][n0] = f2bf(vp0.x); vT_s[0][d0 + 1][n0] = f2bf(vp0.y);
        vT_s[0][d0 + 2][n0] = f2bf(vp0.z); vT_s[0][d0 + 3][n0] = f2bf(vp0.w);
        if (s1) {
            ushort4 o1;
            o1.x = f2bf(kp1.x); o1.y = f2bf(kp1.y); o1.z = f2bf(kp1.z); o1.w = f2bf(kp1.w);
            *reinterpret_cast<ushort4*>(&k_s[0][n1][f1 * 4]) = o1;
            const int d1 = f1 * 4;
            vT_s[0][d1 + 0][n1] = f2bf(vp1.x); vT_s[0][d1 + 1][n1] = f2bf(vp1.y);
            vT_s[0][d1 + 2][n1] = f2bf(vp1.z); vT_s[0][d1 + 3][n1] = f2bf(vp1.w);
        }
    }
    __syncthreads();

    f32x4 pacc[12];
#pragma unroll
    for (int ct = 0; ct < 12; ++ct) pacc[ct] = fzero;

    for (int h = 0; h < NH; ++h) {
        const int cur = h & 1;

        // ---- Q fragment from prefetched regs ----
        u16x8 qv;
        qv[0] = f2bf(qpA.x * SCALE); qv[1] = f2bf(qpA.y * SCALE);
        qv[2] = f2bf(qpA.z * SCALE); qv[3] = f2bf(qpA.w * SCALE);
        qv[4] = f2bf(qpB.x * SCALE); qv[5] = f2bf(qpB.y * SCALE);
        qv[6] = f2bf(qpB.z * SCALE); qv[7] = f2bf(qpB.w * SCALE);
        const bf16x8 aq = __builtin_bit_cast(bf16x8, qv);

        // ---- QK^T ----
        f32x4 acc[4];
#pragma unroll
        for (int t = 0; t < 4; ++t) {
            const bf16x8 bk = *reinterpret_cast<const bf16x8*>(&k_s[cur][16 * t + lc][8 * lg]);
            acc[t] = __builtin_amdgcn_mfma_f32_16x16x32_bf16(aq, bk, fzero, 0, 0, 0);
        }

        // ---- issue prefetch for h+1 (latency hides under softmax+PV+proj) ----
        if (h + 1 < NH) {
            const float* qn = qptr + (h + 1) * 32;
            qpA = *reinterpret_cast<const float4*>(qn);
            qpB = *reinterpret_cast<const float4*>(qn + 4);
            kp0 = *reinterpret_cast<const float4*>(qkvb + n0 * 576 + CDIM + (h + 1) * 32 + f0 * 4);
            vp0 = *reinterpret_cast<const float4*>(qkvb + n0 * 576 + 2 * CDIM + (h + 1) * 32 + f0 * 4);
            if (s1) {
                kp1 = *reinterpret_cast<const float4*>(qkvb + n1 * 576 + CDIM + (h + 1) * 32 + f1 * 4);
                vp1 = *reinterpret_cast<const float4*>(qkvb + n1 * 576 + 2 * CDIM + (h + 1) * 32 + f1 * 4);
            }
        }

        // ---- softmax (rows wave-private) ----
#pragma unroll
        for (int r = 0; r < 4; ++r) {
            const int i = 16 * wv + 4 * lg + r;
            float vals[4];
#pragma unroll
            for (int t = 0; t < 4; ++t) {
                const int idx = r * 4 + t;
                const u32 bp = bidx2[idx >> 1];
                const int bi = (idx & 1) ? (int)(bp >> 16) : (int)(bp & 0xFFFFu);
                const float bias = bias_table[bi + h];
                float v = acc[t][r] + bias + (((mbits >> idx) & 1u) ? -100.f : 0.f);
                vals[t] = ((vbits >> idx) & 1u) ? -1e30f : v;
            }
            float m = fmaxf(fmaxf(vals[0], vals[1]), fmaxf(vals[2], vals[3]));
#pragma unroll
            for (int off = 1; off < 16; off <<= 1) m = fmaxf(m, __shfl_xor(m, off, 16));
            float e[4], s = 0.f;
#pragma unroll
            for (int t = 0; t < 4; ++t) { e[t] = __expf(vals[t] - m); s += e[t]; }
#pragma unroll
            for (int off = 1; off < 16; off <<= 1) s += __shfl_xor(s, off, 16);
            const float rs = 1.0f / s;
#pragma unroll
            for (int t = 0; t < 4; ++t)
                p_s[i][16 * t + lc] = f2bf(e[t] * rs);
        }

        // ---- PV: x_h[16x32] per wave ----
        f32x4 xacc[2] = {fzero, fzero};
#pragma unroll
        for (int ks = 0; ks < 2; ++ks) {
            const bf16x8 pa = *reinterpret_cast<const bf16x8*>(&p_s[16 * wv + lc][32 * ks + 8 * lg]);
#pragma unroll
            for (int ct = 0; ct < 2; ++ct) {
                const bf16x8 vb = *reinterpret_cast<const bf16x8*>(&vT_s[cur][16 * ct + lc][32 * ks + 8 * lg]);
                xacc[ct] = __builtin_amdgcn_mfma_f32_16x16x32_bf16(pa, vb, xacc[ct], 0, 0, 0);
            }
        }

        // ---- x_h -> own p_s stripe cols 0..31 (same-wave, in-order DS) ----
#pragma unroll
        for (int ct = 0; ct < 2; ++ct)
#pragma unroll
            for (int r = 0; r < 4; ++r)
                p_s[16 * wv + 4 * lg + r][16 * ct + lc] = f2bf(xacc[ct][r]);

        // ---- fused proj: pacc += x_h @ W_h^T (rows 16wv.., all 192 cols) ----
        const bf16x8 af = *reinterpret_cast<const bf16x8*>(&p_s[16 * wv + lc][8 * lg]);
#pragma unroll
        for (int ct = 0; ct < 12; ++ct) {
            const bf16x8 bw = *reinterpret_cast<const bf16x8*>(wb + (16 * ct + lc) * CDIM + h * 32 + 8 * lg);
            pacc[ct] = __builtin_amdgcn_mfma_f32_16x16x32_bf16(af, bw, pacc[ct], 0, 0, 0);
        }

        // ---- stage h+1 into other buffer, single barrier per head ----
        if (h + 1 < NH) {
            const int nb = cur ^ 1;
            ushort4 o;
            o.x = f2bf(kp0.x); o.y = f2bf(kp0.y); o.z = f2bf(kp0.z); o.w = f2bf(kp0.w);
            *reinterpret_cast<ushort4*>(&k_s[nb][n0][f0 * 4]) = o;
            const int d0 = f0 * 4;
            vT_s[nb][d0 + 0][n0] = f2bf(vp0.x); vT_s[nb][d0 + 1][n0] = f2bf(vp0.y);
            vT_s[nb][d0 + 2][n0] = f2bf(vp0.z); vT_s[nb][d0 + 3][n0] = f2bf(vp0.w);
            if (s1) {
                ushort4 o1;
                o1.x = f2bf(kp1.x); o1.y = f2bf(kp1.y); o1.z = f2bf(kp1.z); o1.w = f2bf(kp1.w);
                *reinterpret_cast<ushort4*>(&k_s[nb][n1][f1 * 4]) = o1;
                const int d1 = f1 * 4;
                vT_s[nb][d1 + 0][n1] = f2bf(vp1.x); vT_s[nb][d1 + 1][n1] = f2bf(vp1.y);
                vT_s[nb][d1 + 2][n1] = f2bf(vp1.z); vT_s[nb][d1 + 3][n1] = f2bf(vp1.w);
            }
            __syncthreads();
        }
    }

    // ---- epilogue: out rows 16wv+4lg+r, all 192 cols ----
#pragma unroll
    for (int ct = 0; ct < 12; ++ct) {
        const int c = 16 * ct + lc;
        const float pb = proj_b[c];
#pragma unroll
        for (int r = 0; r < 4; ++r) {
            const int i = 16 * wv + 4 * lg + r;
            if (i < NTOK)
                out[(size_t)b * (NTOK * CDIM) + i * CDIM + c] = pacc[ct][r] + pb;
        }
    }
}

extern "C" void kernel_launch(void* const* d_in, const int* in_sizes, int n_in,
                              void* d_out, int out_size, void* d_ws, size_t ws_size,
                              hipStream_t stream) {
    const float* qkv        = (const float*)d_in[0];
    const int*   rpi        = (const int*)d_in[1];
    const float* mask       = (const float*)d_in[2];
    const float* bias_table = (const float*)d_in[3];
    const float* proj_w     = (const float*)d_in[4];
    const float* proj_b     = (const float*)d_in[5];
    float* out = (float*)d_out;
    u16* wb = (u16*)d_ws;  // bf16 copy of proj_w (73728 B)

    const int nblk = in_sizes[0] / (NTOK * 3 * CDIM);  // 8192 windows

    build_wb<<<(CDIM * CDIM + 255) / 256, 256, 0, stream>>>(proj_w, wb);
    swin_attn<<<nblk, 256, 0, stream>>>(qkv, rpi, mask, bias_table, wb, proj_b, out);
}

// Round 5
// 809.441 us; speedup vs baseline: 1.5487x; 1.5487x over previous
//
#include <hip/hip_runtime.h>

#define NH 6
#define NTOK 49
#define CDIM 192
#define NWIN 1024
#define SCALE 0.17677669529663687f

typedef __bf16 bf16x8 __attribute__((ext_vector_type(8)));
typedef float f32x4 __attribute__((ext_vector_type(4)));
typedef unsigned short u16;
typedef unsigned int u32;

__device__ __forceinline__ u16 bfr(float x) { return __builtin_bit_cast(u16, (__bf16)x); }

__global__ void build_wb(const float* __restrict__ w, u16* __restrict__ wb) {
    int i = blockIdx.x * 256 + threadIdx.x;
    if (i < CDIM * CDIM) wb[i] = bfr(w[i]);
}

// ---------------- Kernel A: attention, writes x (bf16) to workspace ----------------
// One block per window, 256 thr = 4 waves. Only V staged in LDS (double-buffered,
// 1 barrier/head); Q/K fragments direct global->reg (32B/lane row slices, L1/L2-hit
// redundancy). No proj accumulator -> low VGPR, LDS 18432 B -> high occupancy.
__global__ __launch_bounds__(256, 4)
void attn_x(const float* __restrict__ qkv, const int* __restrict__ rpi,
            const float* __restrict__ mask, const float* __restrict__ bias_table,
            u16* __restrict__ xout) {
    __shared__ u16 vT_s[2][32][72];  // V^T bf16 [d][n], row 144B
    __shared__ u16 p_s[64][72];      // P / x_h staging, wave-private 16-row stripes

    const int tid = threadIdx.x;
    const int b = blockIdx.x;
    const int wn = b & (NWIN - 1);
    const int wv = tid >> 6;
    const int lane = tid & 63;
    const int lg = lane >> 4;
    const int lc = lane & 15;

    const float* qkvb = qkv + (size_t)b * (NTOK * 3 * CDIM);
    const float* mrow = mask + (size_t)wn * (NTOK * NTOK);
    const f32x4 fzero = {0.f, 0.f, 0.f, 0.f};

    // V staging distribution: item idx in [0,392): n=idx>>3, f=idx&7
    const int n0 = tid >> 3, f0 = tid & 7;
    const bool s1 = tid < 136;
    const int n1 = (tid + 256) >> 3, f1 = (tid + 256) & 7;
    const float* vb0 = qkvb + n0 * 576 + 2 * CDIM + f0 * 4;
    const float* vb1 = qkvb + n1 * 576 + 2 * CDIM + f1 * 4;

    // per-lane Q row pointer (clamped; pad rows masked later)
    const int qrow = (16 * wv + lc < NTOK) ? 16 * wv + lc : NTOK - 1;
    const float* qptr = qkvb + (size_t)qrow * 576 + 8 * lg;
    // per-lane K row pointers for the 4 column tiles
    const float* kptr[4];
#pragma unroll
    for (int t = 0; t < 4; ++t) {
        const int krow = (16 * t + lc < NTOK) ? 16 * t + lc : NTOK - 1;
        kptr[t] = qkvb + (size_t)krow * 576 + CDIM + 8 * lg;
    }

    // ---- hoist rpi/mask: 8 packed index regs + 2 bitmask regs ----
    u32 bidx2[8];
    u32 mbits = 0, vbits = 0;
#pragma unroll
    for (int r = 0; r < 4; ++r) {
        const int i = 16 * wv + 4 * lg + r;
#pragma unroll
        for (int t = 0; t < 4; ++t) {
            const int j = 16 * t + lc;
            const int idx = r * 4 + t;
            const bool valid = (i < NTOK) && (j < NTOK);
            const int ij = valid ? i * NTOK + j : 0;
            const u32 bi = (u32)(rpi[ij] * NH);  // < 1014, fits 16 bits
            if (idx & 1) bidx2[idx >> 1] |= bi << 16; else bidx2[idx >> 1] = bi;
            const float mv = valid ? mrow[ij] : 0.f;
            if (!valid) vbits |= 1u << idx;
            if (mv < -50.f) mbits |= 1u << idx;
        }
    }

    // ---- zero vT pad cols 49..63 once (both buffers; never rewritten) ----
    for (int idx = tid; idx < 512; idx += 256) {
        const int d = idx >> 4, m = idx & 15;
        if (m) { vT_s[0][d][48 + m] = 0; vT_s[1][d][48 + m] = 0; }
    }

    // ---- prefetch + stage V for h=0 ----
    float4 vp0 = *reinterpret_cast<const float4*>(vb0);
    float4 vp1 = {0, 0, 0, 0};
    if (s1) vp1 = *reinterpret_cast<const float4*>(vb1);
    {
        const int d0 = f0 * 4;
        vT_s[0][d0 + 0][n0] = bfr(vp0.x); vT_s[0][d0 + 1][n0] = bfr(vp0.y);
        vT_s[0][d0 + 2][n0] = bfr(vp0.z); vT_s[0][d0 + 3][n0] = bfr(vp0.w);
        if (s1) {
            const int d1 = f1 * 4;
            vT_s[0][d1 + 0][n1] = bfr(vp1.x); vT_s[0][d1 + 1][n1] = bfr(vp1.y);
            vT_s[0][d1 + 2][n1] = bfr(vp1.z); vT_s[0][d1 + 3][n1] = bfr(vp1.w);
        }
    }
    __syncthreads();

    for (int h = 0; h < NH; ++h) {
        const int cur = h & 1;

        // ---- Q fragment direct ----
        const float4 qA = *reinterpret_cast<const float4*>(qptr + h * 32);
        const float4 qB = *reinterpret_cast<const float4*>(qptr + h * 32 + 4);
        bf16x8 aq;
        aq[0] = (__bf16)(qA.x * SCALE); aq[1] = (__bf16)(qA.y * SCALE);
        aq[2] = (__bf16)(qA.z * SCALE); aq[3] = (__bf16)(qA.w * SCALE);
        aq[4] = (__bf16)(qB.x * SCALE); aq[5] = (__bf16)(qB.y * SCALE);
        aq[6] = (__bf16)(qB.z * SCALE); aq[7] = (__bf16)(qB.w * SCALE);

        // ---- K fragments direct + QK^T ----
        f32x4 acc[4];
#pragma unroll
        for (int t = 0; t < 4; ++t) {
            const float4 kA = *reinterpret_cast<const float4*>(kptr[t] + h * 32);
            const float4 kB = *reinterpret_cast<const float4*>(kptr[t] + h * 32 + 4);
            bf16x8 bk;
            bk[0] = (__bf16)kA.x; bk[1] = (__bf16)kA.y; bk[2] = (__bf16)kA.z; bk[3] = (__bf16)kA.w;
            bk[4] = (__bf16)kB.x; bk[5] = (__bf16)kB.y; bk[6] = (__bf16)kB.z; bk[7] = (__bf16)kB.w;
            acc[t] = __builtin_amdgcn_mfma_f32_16x16x32_bf16(aq, bk, fzero, 0, 0, 0);
        }

        // ---- issue V prefetch for h+1 (hides under softmax+PV) ----
        if (h + 1 < NH) {
            vp0 = *reinterpret_cast<const float4*>(vb0 + (h + 1) * 32);
            if (s1) vp1 = *reinterpret_cast<const float4*>(vb1 + (h + 1) * 32);
        }

        // ---- softmax (rows wave-private) ----
#pragma unroll
        for (int r = 0; r < 4; ++r) {
            const int i = 16 * wv + 4 * lg + r;
            float vals[4];
#pragma unroll
            for (int t = 0; t < 4; ++t) {
                const int idx = r * 4 + t;
                const u32 bp = bidx2[idx >> 1];
                const int bi = (idx & 1) ? (int)(bp >> 16) : (int)(bp & 0xFFFFu);
                const float bias = bias_table[bi + h];
                float v = acc[t][r] + bias + (((mbits >> idx) & 1u) ? -100.f : 0.f);
                vals[t] = ((vbits >> idx) & 1u) ? -1e30f : v;
            }
            float m = fmaxf(fmaxf(vals[0], vals[1]), fmaxf(vals[2], vals[3]));
#pragma unroll
            for (int off = 1; off < 16; off <<= 1) m = fmaxf(m, __shfl_xor(m, off, 16));
            float e[4], s = 0.f;
#pragma unroll
            for (int t = 0; t < 4; ++t) { e[t] = __expf(vals[t] - m); s += e[t]; }
#pragma unroll
            for (int off = 1; off < 16; off <<= 1) s += __shfl_xor(s, off, 16);
            const float rs = 1.0f / s;
#pragma unroll
            for (int t = 0; t < 4; ++t)
                p_s[i][16 * t + lc] = bfr(e[t] * rs);
        }

        // ---- PV: x_h[16x32] per wave ----
        f32x4 xacc[2] = {fzero, fzero};
#pragma unroll
        for (int ks = 0; ks < 2; ++ks) {
            const bf16x8 pa = *reinterpret_cast<const bf16x8*>(&p_s[16 * wv + lc][32 * ks + 8 * lg]);
#pragma unroll
            for (int ct = 0; ct < 2; ++ct) {
                const bf16x8 vv = *reinterpret_cast<const bf16x8*>(&vT_s[cur][16 * ct + lc][32 * ks + 8 * lg]);
                xacc[ct] = __builtin_amdgcn_mfma_f32_16x16x32_bf16(pa, vv, xacc[ct], 0, 0, 0);
            }
        }

        // ---- stage V h+1 into other buffer ----
        if (h + 1 < NH) {
            const int nb = cur ^ 1;
            const int d0 = f0 * 4;
            vT_s[nb][d0 + 0][n0] = bfr(vp0.x); vT_s[nb][d0 + 1][n0] = bfr(vp0.y);
            vT_s[nb][d0 + 2][n0] = bfr(vp0.z); vT_s[nb][d0 + 3][n0] = bfr(vp0.w);
            if (s1) {
                const int d1 = f1 * 4;
                vT_s[nb][d1 + 0][n1] = bfr(vp1.x); vT_s[nb][d1 + 1][n1] = bfr(vp1.y);
                vT_s[nb][d1 + 2][n1] = bfr(vp1.z); vT_s[nb][d1 + 3][n1] = bfr(vp1.w);
            }
        }

        // ---- x_h -> p_s stripe (wave-private), coalesced 16B readback -> global ----
#pragma unroll
        for (int ct = 0; ct < 2; ++ct)
#pragma unroll
            for (int r = 0; r < 4; ++r)
                p_s[16 * wv + 4 * lg + r][16 * ct + lc] = bfr(xacc[ct][r]);
        {
            const int xr = 16 * wv + (lane >> 2);
            if (xr < NTOK) {
                const bf16x8 xv = *reinterpret_cast<const bf16x8*>(&p_s[xr][(lane & 3) * 8]);
                *reinterpret_cast<bf16x8*>(xout + ((size_t)b * NTOK + xr) * CDIM + h * 32 + (lane & 3) * 8) = xv;
            }
        }

        if (h + 1 < NH) __syncthreads();
    }
}

// ---------------- Kernel B: out = x @ W^T + b  (M=nblk*49, N=K=192) ----------------
__global__ __launch_bounds__(256, 4)
void proj_gemm(const u16* __restrict__ x, const u16* __restrict__ wb,
               const float* __restrict__ pb, float* __restrict__ out, int mtot) {
    const int tid = threadIdx.x;
    const int wv = tid >> 6, lane = tid & 63, lg = lane >> 4, lc = lane & 15;
    const int m0 = blockIdx.x * 64 + 16 * wv;
    const f32x4 fzero = {0.f, 0.f, 0.f, 0.f};

    f32x4 pacc[12];
#pragma unroll
    for (int ct = 0; ct < 12; ++ct) pacc[ct] = fzero;

    const int arow = (m0 + lc < mtot) ? m0 + lc : mtot - 1;
    const u16* xr = x + (size_t)arow * CDIM;

#pragma unroll
    for (int ks = 0; ks < 6; ++ks) {
        const bf16x8 af = *reinterpret_cast<const bf16x8*>(xr + ks * 32 + 8 * lg);
#pragma unroll
        for (int ct = 0; ct < 12; ++ct) {
            const bf16x8 bw = *reinterpret_cast<const bf16x8*>(wb + (16 * ct + lc) * CDIM + ks * 32 + 8 * lg);
            pacc[ct] = __builtin_amdgcn_mfma_f32_16x16x32_bf16(af, bw, pacc[ct], 0, 0, 0);
        }
    }

#pragma unroll
    for (int ct = 0; ct < 12; ++ct) {
        const int c = 16 * ct + lc;
        const float bb = pb[c];
#pragma unroll
        for (int r = 0; r < 4; ++r) {
            const int m = m0 + 4 * lg + r;
            if (m < mtot) out[(size_t)m * CDIM + c] = pacc[ct][r] + bb;
        }
    }
}

// ---------------- Fallback: R3's fused kernel (proven), if ws too small ----------------
__global__ __launch_bounds__(256, 4)
void swin_attn_fused(const float* __restrict__ qkv, const int* __restrict__ rpi,
                     const float* __restrict__ mask, const float* __restrict__ bias_table,
                     const u16* __restrict__ wb, const float* __restrict__ proj_b,
                     float* __restrict__ out) {
    __shared__ u16 vT_s[32][72];
    __shared__ u16 p_s[64][72];
    __shared__ u16 xb_s[64][200];

    const int tid = threadIdx.x;
    const int b = blockIdx.x;
    const int wn = b & (NWIN - 1);
    const int wv = tid >> 6;
    const int lane = tid & 63;
    const int lg = lane >> 4;
    const int lc = lane & 15;

    const float* qkvb = qkv + (size_t)b * (NTOK * 3 * CDIM);
    const float* mrow = mask + (size_t)wn * (NTOK * NTOK);
    const f32x4 fzero = {0.f, 0.f, 0.f, 0.f};

    float madd[4][4];
    int bidx[4][4];
#pragma unroll
    for (int r = 0; r < 4; ++r) {
        const int i = 16 * wv + 4 * lg + r;
#pragma unroll
        for (int t = 0; t < 4; ++t) {
            const int j = 16 * t + lc;
            const bool valid = (i < NTOK) && (j < NTOK);
            const int ij = valid ? i * NTOK + j : 0;
            madd[r][t] = valid ? mrow[ij] : -1e30f;
            bidx[r][t] = rpi[ij] * NH;
        }
    }
    for (int idx = tid; idx < 512; idx += 256) {
        const int d = idx >> 4, m = idx & 15;
        if (m) vT_s[d][48 + m] = 0;
    }
    float4 vp0 = {0, 0, 0, 0}, vp1 = {0, 0, 0, 0};
    {
        const int n = tid >> 3, f = tid & 7;
        vp0 = *reinterpret_cast<const float4*>(qkvb + n * 576 + 2 * CDIM + f * 4);
    }
    if (tid + 256 < 392) {
        const int idx = tid + 256, n = idx >> 3, f = idx & 7;
        vp1 = *reinterpret_cast<const float4*>(qkvb + n * 576 + 2 * CDIM + f * 4);
    }

    for (int h = 0; h < NH; ++h) {
        __syncthreads();
        {
            const int n = tid >> 3, d = (tid & 7) * 4;
            vT_s[d + 0][n] = bfr(vp0.x); vT_s[d + 1][n] = bfr(vp0.y);
            vT_s[d + 2][n] = bfr(vp0.z); vT_s[d + 3][n] = bfr(vp0.w);
        }
        if (tid + 256 < 392) {
            const int idx = tid + 256, n = idx >> 3, d = (idx & 7) * 4;
            vT_s[d + 0][n] = bfr(vp1.x); vT_s[d + 1][n] = bfr(vp1.y);
            vT_s[d + 2][n] = bfr(vp1.z); vT_s[d + 3][n] = bfr(vp1.w);
        }
        __syncthreads();
        if (h + 1 < NH) {
            {
                const int n = tid >> 3, f = tid & 7;
                vp0 = *reinterpret_cast<const float4*>(qkvb + n * 576 + 2 * CDIM + (h + 1) * 32 + f * 4);
            }
            if (tid + 256 < 392) {
                const int idx = tid + 256, n = idx >> 3, f = idx & 7;
                vp1 = *reinterpret_cast<const float4*>(qkvb + n * 576 + 2 * CDIM + (h + 1) * 32 + f * 4);
            }
        }
        const int qrow = (16 * wv + lc < NTOK) ? 16 * wv + lc : NTOK - 1;
        const float* qp = qkvb + (size_t)qrow * 576 + h * 32 + 8 * lg;
        const float4 qa4 = *reinterpret_cast<const float4*>(qp);
        const float4 qb4 = *reinterpret_cast<const float4*>(qp + 4);
        bf16x8 aq;
        aq[0] = (__bf16)(qa4.x * SCALE); aq[1] = (__bf16)(qa4.y * SCALE);
        aq[2] = (__bf16)(qa4.z * SCALE); aq[3] = (__bf16)(qa4.w * SCALE);
        aq[4] = (__bf16)(qb4.x * SCALE); aq[5] = (__bf16)(qb4.y * SCALE);
        aq[6] = (__bf16)(qb4.z * SCALE); aq[7] = (__bf16)(qb4.w * SCALE);
        f32x4 acc[4];
#pragma unroll
        for (int t = 0; t < 4; ++t) {
            const int krow = (16 * t + lc < NTOK) ? 16 * t + lc : NTOK - 1;
            const float* kp = qkvb + (size_t)krow * 576 + CDIM + h * 32 + 8 * lg;
            const float4 ka = *reinterpret_cast<const float4*>(kp);
            const float4 kb = *reinterpret_cast<const float4*>(kp + 4);
            bf16x8 bk;
            bk[0] = (__bf16)ka.x; bk[1] = (__bf16)ka.y; bk[2] = (__bf16)ka.z; bk[3] = (__bf16)ka.w;
            bk[4] = (__bf16)kb.x; bk[5] = (__bf16)kb.y; bk[6] = (__bf16)kb.z; bk[7] = (__bf16)kb.w;
            acc[t] = __builtin_amdgcn_mfma_f32_16x16x32_bf16(aq, bk, fzero, 0, 0, 0);
        }
#pragma unroll
        for (int r = 0; r < 4; ++r) {
            const int i = 16 * wv + 4 * lg + r;
            float vals[4];
#pragma unroll
            for (int t = 0; t < 4; ++t)
                vals[t] = acc[t][r] + bias_table[bidx[r][t] + h] + madd[r][t];
            float m = fmaxf(fmaxf(vals[0], vals[1]), fmaxf(vals[2], vals[3]));
#pragma unroll
            for (int off = 1; off < 16; off <<= 1) m = fmaxf(m, __shfl_xor(m, off, 16));
            float e[4], s = 0.f;
#pragma unroll
            for (int t = 0; t < 4; ++t) { e[t] = __expf(vals[t] - m); s += e[t]; }
#pragma unroll
            for (int off = 1; off < 16; off <<= 1) s += __shfl_xor(s, off, 16);
            const float rs = 1.0f / s;
#pragma unroll
            for (int t = 0; t < 4; ++t)
                p_s[i][16 * t + lc] = bfr(e[t] * rs);
        }
        f32x4 xacc[2] = {fzero, fzero};
#pragma unroll
        for (int ks = 0; ks < 2; ++ks) {
            const bf16x8 pa = *reinterpret_cast<const bf16x8*>(&p_s[16 * wv + lc][32 * ks + 8 * lg]);
#pragma unroll
            for (int ct = 0; ct < 2; ++ct) {
                const bf16x8 vv = *reinterpret_cast<const bf16x8*>(&vT_s[16 * ct + lc][32 * ks + 8 * lg]);
                xacc[ct] = __builtin_amdgcn_mfma_f32_16x16x32_bf16(pa, vv, xacc[ct], 0, 0, 0);
            }
        }
#pragma unroll
        for (int ct = 0; ct < 2; ++ct)
#pragma unroll
            for (int r = 0; r < 4; ++r)
                xb_s[16 * wv + 4 * lg + r][h * 32 + 16 * ct + lc] = bfr(xacc[ct][r]);
    }
    __syncthreads();
    f32x4 pacc[3][4];
#pragma unroll
    for (int ct = 0; ct < 3; ++ct)
#pragma unroll
        for (int rt = 0; rt < 4; ++rt) pacc[ct][rt] = fzero;
#pragma unroll
    for (int ks = 0; ks < 6; ++ks) {
        bf16x8 af[4];
#pragma unroll
        for (int rt = 0; rt < 4; ++rt)
            af[rt] = *reinterpret_cast<const bf16x8*>(&xb_s[16 * rt + lc][32 * ks + 8 * lg]);
#pragma unroll
        for (int ct = 0; ct < 3; ++ct) {
            const int c = 48 * wv + 16 * ct + lc;
            const bf16x8 bw = *reinterpret_cast<const bf16x8*>(wb + c * CDIM + 32 * ks + 8 * lg);
#pragma unroll
            for (int rt = 0; rt < 4; ++rt)
                pacc[ct][rt] = __builtin_amdgcn_mfma_f32_16x16x32_bf16(af[rt], bw, pacc[ct][rt], 0, 0, 0);
        }
    }
#pragma unroll
    for (int ct = 0; ct < 3; ++ct) {
        const int c = 48 * wv + 16 * ct + lc;
        const float pb = proj_b[c];
#pragma unroll
        for (int rt = 0; rt < 4; ++rt) {
#pragma unroll
            for (int r = 0; r < 4; ++r) {
                const int i = 16 * rt + 4 * lg + r;
                if (i < NTOK)
                    out[(size_t)b * (NTOK * CDIM) + i * CDIM + c] = pacc[ct][rt][r] + pb;
            }
        }
    }
}

extern "C" void kernel_launch(void* const* d_in, const int* in_sizes, int n_in,
                              void* d_out, int out_size, void* d_ws, size_t ws_size,
                              hipStream_t stream) {
    const float* qkv        = (const float*)d_in[0];
    const int*   rpi        = (const int*)d_in[1];
    const float* mask       = (const float*)d_in[2];
    const float* bias_table = (const float*)d_in[3];
    const float* proj_w     = (const float*)d_in[4];
    const float* proj_b     = (const float*)d_in[5];
    float* out = (float*)d_out;

    u16* wb = (u16*)d_ws;                         // bf16 W, 73728 B
    u16* x  = (u16*)((char*)d_ws + 131072);       // bf16 x, mtot*192*2 B

    const int nblk = in_sizes[0] / (NTOK * 3 * CDIM);  // 8192 windows
    const int mtot = nblk * NTOK;                      // 401408 rows
    const size_t need = 131072 + (size_t)mtot * CDIM * 2;

    build_wb<<<(CDIM * CDIM + 255) / 256, 256, 0, stream>>>(proj_w, wb);
    if (ws_size >= need) {
        attn_x<<<nblk, 256, 0, stream>>>(qkv, rpi, mask, bias_table, x);
        proj_gemm<<<(mtot + 63) / 64, 256, 0, stream>>>(x, wb, proj_b, out, mtot);
    } else {
        swin_attn_fused<<<nblk, 256, 0, stream>>>(qkv, rpi, mask, bias_table, wb, proj_b, out);
    }
}